// Round 1
// baseline (1613.508 us; speedup 1.0000x reference)
//
#include <hip/hip_runtime.h>
#include <hip/hip_cooperative_groups.h>

namespace cg = cooperative_groups;

// Problem constants (match reference)
#define N_UE 100000
#define N_AP 10000
#define N_E  1600000
#define NTILE (N_E / 128)   // 12500 fixed 128-edge tiles
#define GRID  1024          // 4 blocks/CU x 256 CUs -> co-resident (coop-safe)

typedef float f32x4 __attribute__((ext_vector_type(4)));
typedef int   i32x2 __attribute__((ext_vector_type(2)));
typedef short s8b   __attribute__((ext_vector_type(8)));

static __device__ __forceinline__ unsigned short f2bf(float x) {
  union { float f; unsigned int u; } v; v.f = x;
  unsigned int r = v.u + 0x7fffu + ((v.u >> 16) & 1u);  // RTN-even
  return (unsigned short)(r >> 16);
}

// ---------------- phase device functions ----------------

// P0: WTg[col][k] = bf16(W1a[k][col]) (B operand, [n][k]); zero counts + aggW.
static __device__ __forceinline__ void ph0_prep(const float* __restrict__ W1a,
    short* __restrict__ WTg, int* __restrict__ counts, float* __restrict__ aggW) {
  int i = blockIdx.x * 256 + threadIdx.x, n = gridDim.x * 256;
  for (int x = i; x < 128 * 128; x += n) {
    int col = x >> 7, k = x & 127;
    WTg[x] = (short)f2bf(W1a[k * 128 + col]);
  }
  for (int x = i; x < N_AP; x += n) counts[x] = 0;
  for (int x = i; x < N_AP * 128 / 4; x += n)
    ((f32x4*)aggW)[x] = (f32x4){0.f, 0.f, 0.f, 0.f};
}

// P1: histogram of dst
static __device__ __forceinline__ void ph1_hist(const int* __restrict__ dst,
                                                int* __restrict__ counts) {
  int i = blockIdx.x * 256 + threadIdx.x, n = gridDim.x * 256;
  for (; i < N_E; i += n) atomicAdd(&counts[dst[i]], 1);
}

// P2: 40-block local exclusive scans; block totals -> bsum
static __device__ __forceinline__ void ph2_scanlocal(const int* __restrict__ counts,
    int* __restrict__ offsets, int* __restrict__ bsum, int* p) {
  if (blockIdx.x >= 40) return;
  int t = threadIdx.x, idx = blockIdx.x * 256 + t;
  int v = (idx < N_AP) ? counts[idx] : 0;
  p[t] = v;
  __syncthreads();
  for (int d = 1; d < 256; d <<= 1) {
    int s2 = p[t] + ((t >= d) ? p[t - d] : 0);
    __syncthreads();
    p[t] = s2;
    __syncthreads();
  }
  if (idx < N_AP) offsets[idx] = p[t] - v;   // exclusive within block
  if (t == 255) bsum[blockIdx.x] = p[255];
}

// P3: add block bases (offsets then doubles as the scatter cursor)
static __device__ __forceinline__ void ph3_scanbase(int* __restrict__ offsets,
    const int* __restrict__ bsum, int* p) {
  if (blockIdx.x >= 40) return;
  int t = threadIdx.x, idx = blockIdx.x * 256 + t;
  if (t == 0) {
    int b = 0;
    for (int k = 0; k < (int)blockIdx.x; k++) b += bsum[k];
    p[0] = b;
  }
  __syncthreads();
  if (idx < N_AP) offsets[idx] += p[0];
}

// P4: scatter packed (edge 21b | dst.lo11) , (src 17b | dst.hi3) int2 per edge
static __device__ __forceinline__ void ph4_scatter(const int* __restrict__ dst,
    const int* __restrict__ src, int* __restrict__ offsets, i32x2* __restrict__ pair) {
  int i = blockIdx.x * 256 + threadIdx.x, n = gridDim.x * 256;
  for (; i < N_E; i += n) {
    int d = dst[i], s = src[i];
    int pos = atomicAdd(&offsets[d], 1);
    i32x2 v;
    v[0] = i | ((d & 0x7FF) << 21);
    v[1] = s | ((d >> 11) << 17);
    __builtin_nontemporal_store(v, &pair[pos]);
  }
}

// P5: MFMA edge phase over dst-sorted 128-edge tiles; register run-accumulators
// per segment, cross-quad shfl + fp32 atomic flush at AP boundaries.
static __device__ void ph5_edges(const float* __restrict__ edge_hid,
    const float* __restrict__ ue_hid, const short* __restrict__ WTg,
    const float* __restrict__ b1a, const i32x2* __restrict__ pair,
    float* __restrict__ aggW, short (*A)[132], int* segs) {
  int t = threadIdx.x;
  int wave = t >> 6, lane = t & 63, quad = lane >> 4, l16 = lane & 15;

  // B fragments straight from global (16KB, L2-hot): wave owns cols [wave*32, +32)
  s8b bf[2][4];
  for (int ct = 0; ct < 2; ct++)
    for (int ks = 0; ks < 4; ks++)
      bf[ct][ks] = *(const s8b*)&WTg[(wave * 32 + ct * 16 + l16) * 128 +
                                     ks * 32 + quad * 8];
  float bias0 = b1a[wave * 32 + l16];
  float bias1 = b1a[wave * 32 + 16 + l16];

  int runseg = -1;
  float run0 = 0.f, run1 = 0.f;
  auto flush = [&]() {
    if (runseg >= 0) {
      float f0 = run0 + __shfl_xor(run0, 16); f0 += __shfl_xor(f0, 32);
      float f1 = run1 + __shfl_xor(run1, 16); f1 += __shfl_xor(f1, 32);
      if (quad == 0) {
        atomicAdd(&aggW[(size_t)runseg * 128 + wave * 32 + l16], f0);
        atomicAdd(&aggW[(size_t)runseg * 128 + wave * 32 + 16 + l16], f1);
      }
    }
  };

  const int r = t >> 1, h = t & 1;
  for (int tile = blockIdx.x; tile < NTILE; tile += gridDim.x) {
    i32x2 tr = __builtin_nontemporal_load(&pair[(size_t)tile * 128 + r]);
    int e = tr[0] & 0x1FFFFF;
    int d = (int)((unsigned)tr[0] >> 21) | (((tr[1] >> 17) & 7) << 11);
    int s = tr[1] & 0x1FFFF;
    __syncthreads();   // previous tile's LDS reads complete
    if (h == 0) {
      segs[r] = d;
      // edge rows: single-use stream -> nontemporal, keep L2 for ue_hid
      const f32x4* s4 = (const f32x4*)(edge_hid + (size_t)e * 64);
      #pragma unroll
      for (int cc = 0; cc < 8; cc++) {
        f32x4 v = __builtin_nontemporal_load(&s4[cc * 2]);
        f32x4 w = __builtin_nontemporal_load(&s4[cc * 2 + 1]);
        s8b pk;
        pk[0] = (short)f2bf(v[0]); pk[1] = (short)f2bf(v[1]);
        pk[2] = (short)f2bf(v[2]); pk[3] = (short)f2bf(v[3]);
        pk[4] = (short)f2bf(w[0]); pk[5] = (short)f2bf(w[1]);
        pk[6] = (short)f2bf(w[2]); pk[7] = (short)f2bf(w[3]);
        *(s8b*)&A[r][cc * 8] = pk;
      }
    } else {
      // ue rows: reused working set (25.6MB) -> cached loads
      const f32x4* s4 = (const f32x4*)(ue_hid + (size_t)s * 64);
      #pragma unroll
      for (int cc = 0; cc < 8; cc++) {
        f32x4 v = s4[cc * 2];
        f32x4 w = s4[cc * 2 + 1];
        s8b pk;
        pk[0] = (short)f2bf(v[0]); pk[1] = (short)f2bf(v[1]);
        pk[2] = (short)f2bf(v[2]); pk[3] = (short)f2bf(v[3]);
        pk[4] = (short)f2bf(w[0]); pk[5] = (short)f2bf(w[1]);
        pk[6] = (short)f2bf(w[2]); pk[7] = (short)f2bf(w[3]);
        *(s8b*)&A[r][64 + cc * 8] = pk;
      }
    }
    __syncthreads();

    for (int rt = 0; rt < 8; rt++) {
      s8b a0 = *(const s8b*)&A[rt * 16 + l16][0 + quad * 8];
      s8b a1 = *(const s8b*)&A[rt * 16 + l16][32 + quad * 8];
      s8b a2 = *(const s8b*)&A[rt * 16 + l16][64 + quad * 8];
      s8b a3 = *(const s8b*)&A[rt * 16 + l16][96 + quad * 8];
      f32x4 c0 = {0.f, 0.f, 0.f, 0.f}, c1 = {0.f, 0.f, 0.f, 0.f};
      c0 = __builtin_amdgcn_mfma_f32_16x16x32_bf16(a0, bf[0][0], c0, 0, 0, 0);
      c0 = __builtin_amdgcn_mfma_f32_16x16x32_bf16(a1, bf[0][1], c0, 0, 0, 0);
      c0 = __builtin_amdgcn_mfma_f32_16x16x32_bf16(a2, bf[0][2], c0, 0, 0, 0);
      c0 = __builtin_amdgcn_mfma_f32_16x16x32_bf16(a3, bf[0][3], c0, 0, 0, 0);
      c1 = __builtin_amdgcn_mfma_f32_16x16x32_bf16(a0, bf[1][0], c1, 0, 0, 0);
      c1 = __builtin_amdgcn_mfma_f32_16x16x32_bf16(a1, bf[1][1], c1, 0, 0, 0);
      c1 = __builtin_amdgcn_mfma_f32_16x16x32_bf16(a2, bf[1][2], c1, 0, 0, 0);
      c1 = __builtin_amdgcn_mfma_f32_16x16x32_bf16(a3, bf[1][3], c1, 0, 0, 0);
      float t0[4], t1[4];
      #pragma unroll
      for (int j = 0; j < 4; j++) {
        t0[j] = fmaxf(c0[j] + bias0, 0.f);
        t1[j] = fmaxf(c1[j] + bias1, 0.f);
      }
      int gb = rt * 16;
      int sF = segs[gb], sL = segs[gb + 15];
      if (sF == sL) {                       // uniform group (common case)
        if (sF != runseg) { flush(); runseg = sF; run0 = 0.f; run1 = 0.f; }
        run0 += t0[0] + t0[1] + t0[2] + t0[3];
        run1 += t1[0] + t1[1] + t1[2] + t1[3];
      } else {                              // AP boundary inside group (rare)
        int sj[4];
        #pragma unroll
        for (int j = 0; j < 4; j++) sj[j] = segs[gb + quad * 4 + j];
        for (int sg = sF; sg <= sL; sg++) {
          float v0 = 0.f, v1 = 0.f;
          #pragma unroll
          for (int j = 0; j < 4; j++)
            if (sj[j] == sg) { v0 += t0[j]; v1 += t1[j]; }
          if (sg == runseg) { run0 += v0; run1 += v1; }
          else { flush(); runseg = sg; run0 = v0; run1 = v1; }
        }
      }
    }
  }
  flush();
}

// ---------------- kernels ----------------

__global__ __launch_bounds__(256, 4) void apc_all(
    const float* __restrict__ W1a, const float* __restrict__ b1a,
    const float* __restrict__ edge_hid, const float* __restrict__ ue_hid,
    const int* __restrict__ src, const int* __restrict__ dst,
    short* __restrict__ WTg, int* __restrict__ counts, int* __restrict__ offsets,
    int* __restrict__ bsum, i32x2* __restrict__ pair, float* __restrict__ aggW) {
  __shared__ short A[128][132];
  __shared__ int segs[128];
  __shared__ int p[256];
  cg::grid_group g = cg::this_grid();
  ph0_prep(W1a, WTg, counts, aggW);          g.sync();
  ph1_hist(dst, counts);                     g.sync();
  ph2_scanlocal(counts, offsets, bsum, p);   g.sync();
  ph3_scanbase(offsets, bsum, p);            g.sync();
  ph4_scatter(dst, src, offsets, pair);      g.sync();
  ph5_edges(edge_hid, ue_hid, WTg, b1a, pair, aggW, A, segs);
}

// Fallback: same phases as separate sequential launches (no grid sync needed)
__global__ __launch_bounds__(256, 4) void apc_one(int phase,
    const float* __restrict__ W1a, const float* __restrict__ b1a,
    const float* __restrict__ edge_hid, const float* __restrict__ ue_hid,
    const int* __restrict__ src, const int* __restrict__ dst,
    short* __restrict__ WTg, int* __restrict__ counts, int* __restrict__ offsets,
    int* __restrict__ bsum, i32x2* __restrict__ pair, float* __restrict__ aggW) {
  __shared__ short A[128][132];
  __shared__ int segs[128];
  __shared__ int p[256];
  switch (phase) {
    case 0: ph0_prep(W1a, WTg, counts, aggW); break;
    case 1: ph1_hist(dst, counts); break;
    case 2: ph2_scanlocal(counts, offsets, bsum, p); break;
    case 3: ph3_scanbase(offsets, bsum, p); break;
    case 4: ph4_scatter(dst, src, offsets, pair); break;
    case 5: ph5_edges(edge_hid, ue_hid, WTg, b1a, pair, aggW, A, segs); break;
  }
}

// K6: per 16 APs: Y = aggW@W1b + cnt*b1b;  T = relu([ap_hid,Y]@W2a + b2a);
//     out = T@W2b + b2b.  (unchanged except counts[] replaces offsets-diff)
__global__ __launch_bounds__(256) void apk6_mlp2(
    const float* __restrict__ ap_hid, const float* __restrict__ W1b,
    const float* __restrict__ b1b, const float* __restrict__ W2a,
    const float* __restrict__ b2a, const float* __restrict__ W2b,
    const float* __restrict__ b2b, const float* __restrict__ aggW,
    const int* __restrict__ counts, float* __restrict__ out) {
  __shared__ float wbuf[64 * 128];   // 32KB weight tile
  __shared__ float zrows[16 * 128];  // agg rows, later reused as T
  __shared__ float yrows[16 * 128];
  __shared__ float arows[16 * 64];
  __shared__ float cbuf[16];
  int t = threadIdx.x;
  int apb = blockIdx.x * 16;
  for (int i = t; i < 16 * 128 / 4; i += 256)
    ((float4*)zrows)[i] = ((const float4*)(aggW + (size_t)apb * 128))[i];
  for (int i = t; i < 16 * 64 / 4; i += 256)
    ((float4*)arows)[i] = ((const float4*)(ap_hid + (size_t)apb * 64))[i];
  if (t < 16) cbuf[t] = (float)counts[apb + t];
  int j = t & 127, half = t >> 7;
  // ---- phase 1: Y = agg @ W1b + cnt*b1b
  {
    float bb = b1b[j];
    __syncthreads();
    float acc[8];
    for (int r = 0; r < 8; r++) acc[r] = cbuf[half * 8 + r] * bb;
    for (int pp = 0; pp < 2; pp++) {
      __syncthreads();
      for (int i = t; i < 64 * 128 / 4; i += 256)
        ((float4*)wbuf)[i] = ((const float4*)(W1b + pp * 64 * 128))[i];
      __syncthreads();
      for (int k = 0; k < 64; k++) {
        float w = wbuf[k * 128 + j];
        for (int r = 0; r < 8; r++)
          acc[r] += zrows[(half * 8 + r) * 128 + (pp * 64 + k)] * w;
      }
    }
    for (int r = 0; r < 8; r++) yrows[(half * 8 + r) * 128 + j] = acc[r];
  }
  // ---- phase 2: T = relu([ap, Y] @ W2a + b2a), stored into zrows
  {
    float acc2[8];
    float bb = b2a[j];
    for (int r = 0; r < 8; r++) acc2[r] = bb;
    __syncthreads();
    for (int i = t; i < 64 * 128 / 4; i += 256)
      ((float4*)wbuf)[i] = ((const float4*)W2a)[i];
    __syncthreads();
    for (int k = 0; k < 64; k++) {
      float w = wbuf[k * 128 + j];
      for (int r = 0; r < 8; r++) acc2[r] += arows[(half * 8 + r) * 64 + k] * w;
    }
    for (int pp = 0; pp < 2; pp++) {
      __syncthreads();
      for (int i = t; i < 64 * 128 / 4; i += 256)
        ((float4*)wbuf)[i] = ((const float4*)(W2a + (64 + pp * 64) * 128))[i];
      __syncthreads();
      for (int k = 0; k < 64; k++) {
        float w = wbuf[k * 128 + j];
        for (int r = 0; r < 8; r++)
          acc2[r] += yrows[(half * 8 + r) * 128 + (pp * 64 + k)] * w;
      }
    }
    __syncthreads();
    for (int r = 0; r < 8; r++)
      zrows[(half * 8 + r) * 128 + j] = fmaxf(acc2[r], 0.f);
  }
  // ---- phase 3: out = T @ W2b + b2b
  {
    __syncthreads();
    for (int i = t; i < 128 * 64 / 4; i += 256)
      ((float4*)wbuf)[i] = ((const float4*)W2b)[i];
    __syncthreads();
    int i2 = t & 63, q = t >> 6;
    float acc3[4];
    float bb = b2b[i2];
    for (int r = 0; r < 4; r++) acc3[r] = bb;
    for (int k = 0; k < 128; k++) {
      float w = wbuf[k * 64 + i2];
      for (int r = 0; r < 4; r++) acc3[r] += zrows[(q * 4 + r) * 128 + k] * w;
    }
    for (int r = 0; r < 4; r++)
      out[(size_t)(apb + q * 4 + r) * 64 + i2] = acc3[r];
  }
}

extern "C" void kernel_launch(void* const* d_in, const int* in_sizes, int n_in,
                              void* d_out, int out_size, void* d_ws, size_t ws_size,
                              hipStream_t stream) {
  const float* ue_hid   = (const float*)d_in[0];
  const float* ap_hid   = (const float*)d_in[1];
  const float* edge_hid = (const float*)d_in[2];
  const int*   src      = (const int*)d_in[3];
  const int*   dst      = (const int*)d_in[4];
  const float* W1a      = (const float*)d_in[5];
  const float* b1a      = (const float*)d_in[6];
  const float* W1b      = (const float*)d_in[7];
  const float* b1b      = (const float*)d_in[8];
  const float* W2a      = (const float*)d_in[9];
  const float* b2a      = (const float*)d_in[10];
  const float* W2b      = (const float*)d_in[11];
  const float* b2b      = (const float*)d_in[12];
  float* out = (float*)d_out;

  unsigned char* ws = (unsigned char*)d_ws;
  short* WTg    = (short*)(ws);                  //     32,768 B
  int* counts   = (int*)(ws + 32768);            //     40,960 B (padded)
  int* offsets  = (int*)(ws + 73728);            //     40,960 B (doubles as cursor)
  int* bsum     = (int*)(ws + 114688);           //      4,096 B (40 used)
  float* aggW   = (float*)(ws + 118784);         //  5,120,000 B
  i32x2* pair   = (i32x2*)(ws + 5238784);        // 12,800,000 B
  // total: 18,038,784 B of d_ws

  void* args[] = {(void*)&W1a, (void*)&b1a, (void*)&edge_hid, (void*)&ue_hid,
                  (void*)&src, (void*)&dst, (void*)&WTg, (void*)&counts,
                  (void*)&offsets, (void*)&bsum, (void*)&pair, (void*)&aggW};
  hipError_t cerr = hipLaunchCooperativeKernel((void*)apc_all, dim3(GRID), dim3(256),
                                               args, 0, stream);
  if (cerr != hipSuccess) {
    // fallback: sequential phase launches (kernel boundaries provide the syncs)
    for (int p = 0; p < 6; p++)
      apc_one<<<GRID, 256, 0, stream>>>(p, W1a, b1a, edge_hid, ue_hid, src, dst,
                                        WTg, counts, offsets, bsum, pair, aggW);
  }
  apk6_mlp2<<<N_AP / 16, 256, 0, stream>>>(ap_hid, W1b, b1b, W2a, b2a, W2b, b2b,
                                           aggW, counts, out);
}

// Round 2
// 829.033 us; speedup vs baseline: 1.9463x; 1.9463x over previous
//
#include <hip/hip_runtime.h>

// Problem constants (match reference)
#define N_UE 100000
#define N_AP 10000
#define N_E  1600000
#define NTILE (N_E / 128)   // 12500 fixed 128-edge tiles

typedef float f32x4 __attribute__((ext_vector_type(4)));
typedef int   i32x2 __attribute__((ext_vector_type(2)));
typedef short s8b   __attribute__((ext_vector_type(8)));
typedef short s4b   __attribute__((ext_vector_type(4)));

static __device__ __forceinline__ unsigned short f2bf(float x) {
  union { float f; unsigned int u; } v; v.f = x;
  unsigned int r = v.u + 0x7fffu + ((v.u >> 16) & 1u);  // RTN-even
  return (unsigned short)(r >> 16);
}

// K0: WTg[col][k] = bf16(W1a[k][col]) (B operand, [n][k]); zero counts + aggW.
__global__ void apk0_prep(const float* __restrict__ W1a, short* __restrict__ WTg,
                          int* __restrict__ counts, float* __restrict__ aggW) {
  int i = blockIdx.x * 256 + threadIdx.x, n = gridDim.x * 256;
  for (int x = i; x < 128 * 128; x += n) {
    int col = x >> 7, k = x & 127;
    WTg[x] = (short)f2bf(W1a[k * 128 + col]);
  }
  for (int x = i; x < N_AP; x += n) counts[x] = 0;
  for (int x = i; x < N_AP * 128 / 4; x += n)
    ((f32x4*)aggW)[x] = (f32x4){0.f, 0.f, 0.f, 0.f};
}

// K2: histogram of dst (high occupancy, 8 VGPR)
__global__ void apk2_hist(const int* __restrict__ dst, int* __restrict__ counts) {
  int i = blockIdx.x * blockDim.x + threadIdx.x;
  int stride = gridDim.x * blockDim.x;
  for (; i < N_E; i += stride) atomicAdd(&counts[dst[i]], 1);
}

// K3a: 40-block local exclusive scans; block totals -> bsum
__global__ __launch_bounds__(256) void apk3a_scanlocal(
    const int* __restrict__ counts, int* __restrict__ offsets,
    int* __restrict__ bsum) {
  __shared__ int p[256];
  int t = threadIdx.x, idx = blockIdx.x * 256 + t;
  int v = (idx < N_AP) ? counts[idx] : 0;
  p[t] = v;
  __syncthreads();
  for (int d = 1; d < 256; d <<= 1) {
    int s2 = p[t] + ((t >= d) ? p[t - d] : 0);
    __syncthreads();
    p[t] = s2;
    __syncthreads();
  }
  if (idx < N_AP) offsets[idx] = p[t] - v;   // exclusive within block
  if (t == 255) bsum[blockIdx.x] = p[255];
}

// K3b: add block bases (offsets then doubles as the scatter cursor)
__global__ __launch_bounds__(256) void apk3b_scanbase(
    int* __restrict__ offsets, const int* __restrict__ bsum) {
  __shared__ int base;
  int t = threadIdx.x, idx = blockIdx.x * 256 + t;
  if (t == 0) {
    int b = 0;
    for (int k = 0; k < (int)blockIdx.x; k++) b += bsum[k];
    base = b;
  }
  __syncthreads();
  if (idx < N_AP) offsets[idx] += base;
}

// K4: scatter packed (edge 21b | dst.lo11) , (src 17b | dst.hi3) int2 per edge
__global__ void apk4_scatter(const int* __restrict__ dst, const int* __restrict__ src,
                             int* __restrict__ offsets, i32x2* __restrict__ pair) {
  int i = blockIdx.x * blockDim.x + threadIdx.x;
  int stride = gridDim.x * blockDim.x;
  for (; i < N_E; i += stride) {
    int d = dst[i], s = src[i];
    int pos = atomicAdd(&offsets[d], 1);
    i32x2 v;
    v[0] = i | ((d & 0x7FF) << 21);
    v[1] = s | ((d >> 11) << 17);
    pair[pos] = v;
  }
}

// K5: MFMA edge phase over dst-sorted 128-edge tiles.
// Gather is COALESCED: 16 lanes cooperate per 256B row-half (lane = chunk),
// row indices broadcast via LDS; 16 independent loads in flight per thread.
// Segment-reduce rows by dst (sorted) with per-quad register run-accumulators;
// cross-quad shfl + fp32 atomic flush only at AP boundaries.
__global__ __launch_bounds__(256, 4) void apk5_edges(
    const float* __restrict__ edge_hid, const float* __restrict__ ue_hid,
    const short* __restrict__ WTg, const float* __restrict__ b1a,
    const i32x2* __restrict__ pair, float* __restrict__ aggW) {
  __shared__ short A[128][132];    // A operand [edge][k] bf16, pitch 132
  __shared__ int segs[128];
  __shared__ int eix[128];
  __shared__ int six[128];
  int t = threadIdx.x;
  int wave = t >> 6, lane = t & 63, quad = lane >> 4, l16 = lane & 15;

  // B fragments straight from global (32KB, L2-hot): wave owns cols [wave*32,+32)
  s8b bf[2][4];
  for (int ct = 0; ct < 2; ct++)
    for (int ks = 0; ks < 4; ks++)
      bf[ct][ks] = *(const s8b*)&WTg[(wave * 32 + ct * 16 + l16) * 128 +
                                     ks * 32 + quad * 8];
  float bias0 = b1a[wave * 32 + l16];
  float bias1 = b1a[wave * 32 + 16 + l16];

  int runseg = -1;
  float run0 = 0.f, run1 = 0.f;
  auto flush = [&]() {
    if (runseg >= 0) {
      float f0 = run0 + __shfl_xor(run0, 16); f0 += __shfl_xor(f0, 32);
      float f1 = run1 + __shfl_xor(run1, 16); f1 += __shfl_xor(f1, 32);
      if (quad == 0) {
        atomicAdd(&aggW[(size_t)runseg * 128 + wave * 32 + l16], f0);
        atomicAdd(&aggW[(size_t)runseg * 128 + wave * 32 + 16 + l16], f1);
      }
    }
  };

  const int r8 = t >> 5, half = (t >> 4) & 1, chunk = t & 15;
  for (int tile = blockIdx.x; tile < NTILE; tile += gridDim.x) {
    __syncthreads();   // previous tile's LDS reads (A, segs) complete
    if (t < 128) {
      i32x2 tr = pair[(size_t)tile * 128 + t];
      segs[t] = (int)((unsigned)tr[0] >> 21) | (((tr[1] >> 17) & 7) << 11);
      eix[t] = tr[0] & 0x1FFFFF;
      six[t] = tr[1] & 0x1FFFF;
    }
    __syncthreads();
    {
      // hoist the 16 row bases (static-indexed -> registers), then 16
      // independent coalesced 16B loads per thread
      const float* bases[16];
      #pragma unroll
      for (int it = 0; it < 16; it++) {
        int row = it * 8 + r8;
        bases[it] = half ? (ue_hid + (size_t)six[row] * 64)
                         : (edge_hid + (size_t)eix[row] * 64);
      }
      #pragma unroll
      for (int it = 0; it < 16; it++) {
        int row = it * 8 + r8;
        f32x4 v = ((const f32x4*)bases[it])[chunk];
        s4b pk;
        pk[0] = (short)f2bf(v[0]); pk[1] = (short)f2bf(v[1]);
        pk[2] = (short)f2bf(v[2]); pk[3] = (short)f2bf(v[3]);
        *(s4b*)&A[row][half * 64 + chunk * 4] = pk;
      }
    }
    __syncthreads();

    for (int rt = 0; rt < 8; rt++) {
      s8b a0 = *(const s8b*)&A[rt * 16 + l16][0 + quad * 8];
      s8b a1 = *(const s8b*)&A[rt * 16 + l16][32 + quad * 8];
      s8b a2 = *(const s8b*)&A[rt * 16 + l16][64 + quad * 8];
      s8b a3 = *(const s8b*)&A[rt * 16 + l16][96 + quad * 8];
      f32x4 c0 = {0.f, 0.f, 0.f, 0.f}, c1 = {0.f, 0.f, 0.f, 0.f};
      c0 = __builtin_amdgcn_mfma_f32_16x16x32_bf16(a0, bf[0][0], c0, 0, 0, 0);
      c0 = __builtin_amdgcn_mfma_f32_16x16x32_bf16(a1, bf[0][1], c0, 0, 0, 0);
      c0 = __builtin_amdgcn_mfma_f32_16x16x32_bf16(a2, bf[0][2], c0, 0, 0, 0);
      c0 = __builtin_amdgcn_mfma_f32_16x16x32_bf16(a3, bf[0][3], c0, 0, 0, 0);
      c1 = __builtin_amdgcn_mfma_f32_16x16x32_bf16(a0, bf[1][0], c1, 0, 0, 0);
      c1 = __builtin_amdgcn_mfma_f32_16x16x32_bf16(a1, bf[1][1], c1, 0, 0, 0);
      c1 = __builtin_amdgcn_mfma_f32_16x16x32_bf16(a2, bf[1][2], c1, 0, 0, 0);
      c1 = __builtin_amdgcn_mfma_f32_16x16x32_bf16(a3, bf[1][3], c1, 0, 0, 0);
      float t0[4], t1[4];
      #pragma unroll
      for (int j = 0; j < 4; j++) {
        t0[j] = fmaxf(c0[j] + bias0, 0.f);
        t1[j] = fmaxf(c1[j] + bias1, 0.f);
      }
      int gb = rt * 16;
      int sF = segs[gb], sL = segs[gb + 15];
      if (sF == sL) {                       // uniform group (common case)
        if (sF != runseg) { flush(); runseg = sF; run0 = 0.f; run1 = 0.f; }
        run0 += t0[0] + t0[1] + t0[2] + t0[3];
        run1 += t1[0] + t1[1] + t1[2] + t1[3];
      } else {                              // AP boundary inside group (rare)
        int sj[4];
        #pragma unroll
        for (int j = 0; j < 4; j++) sj[j] = segs[gb + quad * 4 + j];
        for (int sg = sF; sg <= sL; sg++) {
          float v0 = 0.f, v1 = 0.f;
          #pragma unroll
          for (int j = 0; j < 4; j++)
            if (sj[j] == sg) { v0 += t0[j]; v1 += t1[j]; }
          if (sg == runseg) { run0 += v0; run1 += v1; }
          else { flush(); runseg = sg; run0 = v0; run1 = v1; }
        }
      }
    }
  }
  flush();
}

// K6: per 16 APs: Y = aggW@W1b + cnt*b1b;  T = relu([ap_hid,Y]@W2a + b2a);
//     out = T@W2b + b2b.  All fp32, weights staged through a 32KB LDS buffer.
__global__ __launch_bounds__(256) void apk6_mlp2(
    const float* __restrict__ ap_hid, const float* __restrict__ W1b,
    const float* __restrict__ b1b, const float* __restrict__ W2a,
    const float* __restrict__ b2a, const float* __restrict__ W2b,
    const float* __restrict__ b2b, const float* __restrict__ aggW,
    const int* __restrict__ counts, float* __restrict__ out) {
  __shared__ float wbuf[64 * 128];   // 32KB weight tile
  __shared__ float zrows[16 * 128];  // agg rows, later reused as T
  __shared__ float yrows[16 * 128];
  __shared__ float arows[16 * 64];
  __shared__ float cbuf[16];
  int t = threadIdx.x;
  int apb = blockIdx.x * 16;
  for (int i = t; i < 16 * 128 / 4; i += 256)
    ((float4*)zrows)[i] = ((const float4*)(aggW + (size_t)apb * 128))[i];
  for (int i = t; i < 16 * 64 / 4; i += 256)
    ((float4*)arows)[i] = ((const float4*)(ap_hid + (size_t)apb * 64))[i];
  if (t < 16) cbuf[t] = (float)counts[apb + t];
  int j = t & 127, half = t >> 7;
  // ---- phase 1: Y = agg @ W1b + cnt*b1b
  {
    float bb = b1b[j];
    __syncthreads();
    float acc[8];
    for (int r = 0; r < 8; r++) acc[r] = cbuf[half * 8 + r] * bb;
    for (int pp = 0; pp < 2; pp++) {
      __syncthreads();
      for (int i = t; i < 64 * 128 / 4; i += 256)
        ((float4*)wbuf)[i] = ((const float4*)(W1b + pp * 64 * 128))[i];
      __syncthreads();
      for (int k = 0; k < 64; k++) {
        float w = wbuf[k * 128 + j];
        for (int r = 0; r < 8; r++)
          acc[r] += zrows[(half * 8 + r) * 128 + (pp * 64 + k)] * w;
      }
    }
    for (int r = 0; r < 8; r++) yrows[(half * 8 + r) * 128 + j] = acc[r];
  }
  // ---- phase 2: T = relu([ap, Y] @ W2a + b2a), stored into zrows
  {
    float acc2[8];
    float bb = b2a[j];
    for (int r = 0; r < 8; r++) acc2[r] = bb;
    __syncthreads();
    for (int i = t; i < 64 * 128 / 4; i += 256)
      ((float4*)wbuf)[i] = ((const float4*)W2a)[i];
    __syncthreads();
    for (int k = 0; k < 64; k++) {
      float w = wbuf[k * 128 + j];
      for (int r = 0; r < 8; r++) acc2[r] += arows[(half * 8 + r) * 64 + k] * w;
    }
    for (int pp = 0; pp < 2; pp++) {
      __syncthreads();
      for (int i = t; i < 64 * 128 / 4; i += 256)
        ((float4*)wbuf)[i] = ((const float4*)(W2a + (64 + pp * 64) * 128))[i];
      __syncthreads();
      for (int k = 0; k < 64; k++) {
        float w = wbuf[k * 128 + j];
        for (int r = 0; r < 8; r++)
          acc2[r] += yrows[(half * 8 + r) * 128 + (pp * 64 + k)] * w;
      }
    }
    __syncthreads();
    for (int r = 0; r < 8; r++)
      zrows[(half * 8 + r) * 128 + j] = fmaxf(acc2[r], 0.f);
  }
  // ---- phase 3: out = T @ W2b + b2b
  {
    __syncthreads();
    for (int i = t; i < 128 * 64 / 4; i += 256)
      ((float4*)wbuf)[i] = ((const float4*)W2b)[i];
    __syncthreads();
    int i2 = t & 63, q = t >> 6;
    float acc3[4];
    float bb = b2b[i2];
    for (int r = 0; r < 4; r++) acc3[r] = bb;
    for (int k = 0; k < 128; k++) {
      float w = wbuf[k * 64 + i2];
      for (int r = 0; r < 4; r++) acc3[r] += zrows[(q * 4 + r) * 128 + k] * w;
    }
    for (int r = 0; r < 4; r++)
      out[(size_t)(apb + q * 4 + r) * 64 + i2] = acc3[r];
  }
}

extern "C" void kernel_launch(void* const* d_in, const int* in_sizes, int n_in,
                              void* d_out, int out_size, void* d_ws, size_t ws_size,
                              hipStream_t stream) {
  const float* ue_hid   = (const float*)d_in[0];
  const float* ap_hid   = (const float*)d_in[1];
  const float* edge_hid = (const float*)d_in[2];
  const int*   src      = (const int*)d_in[3];
  const int*   dst      = (const int*)d_in[4];
  const float* W1a      = (const float*)d_in[5];
  const float* b1a      = (const float*)d_in[6];
  const float* W1b      = (const float*)d_in[7];
  const float* b1b      = (const float*)d_in[8];
  const float* W2a      = (const float*)d_in[9];
  const float* b2a      = (const float*)d_in[10];
  const float* W2b      = (const float*)d_in[11];
  const float* b2b      = (const float*)d_in[12];
  float* out = (float*)d_out;

  unsigned char* ws = (unsigned char*)d_ws;
  short* WTg    = (short*)(ws);                  //     32,768 B
  int* counts   = (int*)(ws + 32768);            //     40,960 B (padded)
  int* offsets  = (int*)(ws + 73728);            //     40,960 B (doubles as cursor)
  int* bsum     = (int*)(ws + 114688);           //      4,096 B (40 used)
  float* aggW   = (float*)(ws + 118784);         //  5,120,000 B
  i32x2* pair   = (i32x2*)(ws + 5238784);        // 12,800,000 B
  // total: 18,038,784 B of d_ws

  apk0_prep<<<640, 256, 0, stream>>>(W1a, WTg, counts, aggW);
  apk2_hist<<<2048, 256, 0, stream>>>(dst, counts);
  apk3a_scanlocal<<<40, 256, 0, stream>>>(counts, offsets, bsum);
  apk3b_scanbase<<<40, 256, 0, stream>>>(offsets, bsum);
  apk4_scatter<<<2048, 256, 0, stream>>>(dst, src, offsets, pair);
  apk5_edges<<<2048, 256, 0, stream>>>(edge_hid, ue_hid, WTg, b1a, pair, aggW);
  apk6_mlp2<<<N_AP / 16, 256, 0, stream>>>(ap_hid, W1b, b1b, W2a, b2a, W2b, b2b,
                                           aggW, counts, out);
}